// Round 3
// baseline (123.902 us; speedup 1.0000x reference)
//
#include <hip/hip_runtime.h>
#include <hip/hip_bf16.h>

// Pipeline (chain = b*768 + c1, 12288 chains; pos in [0,1156) of the 34x34 grid):
//  d_ws  : xt2 [1156][12288] fp32 (chain-major) = 56.8 MB
//  d_out : scratch for bf16 A ([16384][768]) + bf16 W ([768][768]) during GEMM,
//          then fully overwritten with the final cropped output by scan_emit_k.
//  1) convert_x_k     : x fp32 -> A_bf16 [m=(b,ph,pw)][k=(c,py,px)]
//  2) convert_w_k     : w fp32 -> W_bf16
//  3) fill_borders2_k : border pos of xt2 = bias[c1] (coalesced over chains)
//  4) conv_gemm_mfma  : 128x128 MFMA bf16 GEMM (+bias) -> xt2 interior
//  5) scan_emit_k     : sequential stride-32 8-neighbor recurrence per chain,
//                       coalesced chain-major reads, emits final cropped output.

typedef __attribute__((ext_vector_type(8))) short s8v;     // 8 bf16
typedef __attribute__((ext_vector_type(4))) float f4v;     // MFMA acc
typedef __attribute__((ext_vector_type(8))) unsigned short us8;

__device__ __forceinline__ unsigned short f2bf(float f) {
    __hip_bfloat16 h = __float2bfloat16(f);
    return *reinterpret_cast<unsigned short*>(&h);
}

__device__ __forceinline__ void gload_lds16(const void* g, void* l) {
    __builtin_amdgcn_global_load_lds(
        (const __attribute__((address_space(1))) unsigned int*)g,
        (__attribute__((address_space(3))) unsigned int*)l,
        16, 0, 0);
}

// x [16][3][512][512] f32 -> A_bf [16384][768] bf16
__global__ __launch_bounds__(256) void convert_x_k(const float* __restrict__ x,
                                                   unsigned short* __restrict__ a) {
    int g = blockIdx.x * 256 + threadIdx.x;
    int f = g << 3;
    int wc = f & 511;
    int h  = (f >> 9) & 511;
    int cb = f >> 18;
    int c  = cb % 3, b = cb / 3;
    const float4 v0 = *(const float4*)(x + f);
    const float4 v1 = *(const float4*)(x + f + 4);
    int m = (b << 10) + ((h >> 4) << 5) + (wc >> 4);
    int k = (c << 8) + ((h & 15) << 4) + (wc & 15);
    us8 o;
    o[0] = f2bf(v0.x); o[1] = f2bf(v0.y); o[2] = f2bf(v0.z); o[3] = f2bf(v0.w);
    o[4] = f2bf(v1.x); o[5] = f2bf(v1.y); o[6] = f2bf(v1.z); o[7] = f2bf(v1.w);
    *(us8*)(a + (size_t)m * 768 + k) = o;
}

__global__ __launch_bounds__(256) void convert_w_k(const float* __restrict__ w,
                                                   unsigned short* __restrict__ o) {
    int g = blockIdx.x * 256 + threadIdx.x;
    int f = g << 3;
    const float4 v0 = *(const float4*)(w + f);
    const float4 v1 = *(const float4*)(w + f + 4);
    us8 u;
    u[0] = f2bf(v0.x); u[1] = f2bf(v0.y); u[2] = f2bf(v0.z); u[3] = f2bf(v0.w);
    u[4] = f2bf(v1.x); u[5] = f2bf(v1.y); u[6] = f2bf(v1.z); u[7] = f2bf(v1.w);
    *(us8*)(o + f) = u;
}

// xt2[pos][chain] = bias[c1] for the 132 border positions of the 34x34 grid
__global__ __launch_bounds__(256) void fill_borders2_k(const float* __restrict__ bias,
                                                       float* __restrict__ xt2) {
    int tid = blockIdx.x * 256 + threadIdx.x;      // 132 * 12288 exactly
    int chain = tid % 12288;
    int e     = tid / 12288;
    int pos;
    if (e < 34)       pos = e;                      // h1 == 0
    else if (e < 68)  pos = 1122 + (e - 34);        // h1 == 33
    else if (e < 100) pos = (e - 67) * 34;          // w1 == 0, h1 = 1..32
    else              pos = (e - 99) * 34 + 33;     // w1 == 33, h1 = 1..32
    xt2[(size_t)pos * 12288 + chain] = bias[chain % 768];
}

// C[m][n] = sum_k A[m][k] * W[n][k]; 128x128 tile, BK=32, 4 waves
__global__ __launch_bounds__(256) void conv_gemm_mfma_k(const unsigned short* __restrict__ A,
                                                        const unsigned short* __restrict__ W,
                                                        const float* __restrict__ bias,
                                                        float* __restrict__ xt2) {
    __shared__ __align__(16) unsigned short As[128 * 32];
    __shared__ __align__(16) unsigned short Bs[128 * 32];
    const int tid  = threadIdx.x;
    const int lane = tid & 63, wv = tid >> 6;
    const int wr = wv >> 1, wc = wv & 1;
    const int m0 = blockIdx.x << 7, n0 = blockIdx.y << 7;

    f4v acc[4][4] = {};

    const unsigned short* gA = A + (size_t)(m0 + (wv << 5) + (lane >> 2)) * 768 + ((lane & 3) << 3);
    const unsigned short* gB = W + (size_t)(n0 + (wv << 5) + (lane >> 2)) * 768 + ((lane & 3) << 3);
    unsigned short* lA = As + (wv << 10);
    unsigned short* lB = Bs + (wv << 10);

    for (int k0 = 0; k0 < 768; k0 += 32) {
        gload_lds16(gA + k0,            lA);
        gload_lds16(gA + k0 + 16 * 768, lA + 512);
        gload_lds16(gB + k0,            lB);
        gload_lds16(gB + k0 + 16 * 768, lB + 512);
        __syncthreads();
        s8v a[4], b[4];
        #pragma unroll
        for (int mi = 0; mi < 4; ++mi)
            a[mi] = *(const s8v*)(As + (((wr << 6) + (mi << 4) + (lane & 15)) << 5) + ((lane >> 4) << 3));
        #pragma unroll
        for (int ni = 0; ni < 4; ++ni)
            b[ni] = *(const s8v*)(Bs + (((wc << 6) + (ni << 4) + (lane & 15)) << 5) + ((lane >> 4) << 3));
        #pragma unroll
        for (int mi = 0; mi < 4; ++mi)
            #pragma unroll
            for (int ni = 0; ni < 4; ++ni)
                acc[mi][ni] = __builtin_amdgcn_mfma_f32_16x16x32_bf16(a[mi], b[ni], acc[mi][ni], 0, 0, 0);
        __syncthreads();
    }

    #pragma unroll
    for (int ni = 0; ni < 4; ++ni) {
        int n = n0 + (wc << 6) + (ni << 4) + (lane & 15);
        float bv = bias[n];
        #pragma unroll
        for (int mi = 0; mi < 4; ++mi) {
            #pragma unroll
            for (int r = 0; r < 4; ++r) {
                int m  = m0 + (wr << 6) + (mi << 4) + ((lane >> 4) << 2) + r;
                int bb = m >> 10, ph = (m >> 5) & 31, pw = m & 31;
                int pos = (ph + 1) * 34 + (pw + 1);
                xt2[(size_t)pos * 12288 + bb * 768 + n] = acc[mi][ni][r] + bv;
            }
        }
    }
}

// ---- scan + fused crop ----

__device__ __forceinline__ void emit4(float* __restrict__ outb, int fl, float4 o) {
    // fl = c1*1156 + flat (4-aligned). Map to (c,y,x) of the (3,544,544) view.
    unsigned int c = (fl >= 591872) ? 2u : (fl >= 295936 ? 1u : 0u);
    unsigned int rem = (unsigned int)fl - c * 295936u;
    unsigned int y = rem / 544u;
    unsigned int x = rem - y * 544u;
    if (y >= 16u && y < 528u && x >= 16u && x < 528u)
        *(float4*)(outb + (size_t)c * 262144 + (y - 16) * 512 + (x - 16)) = o;
}

__device__ __forceinline__ void emit32(float* __restrict__ outb, int fl0,
                                       const float* __restrict__ v) {
    #pragma unroll
    for (int q = 0; q < 8; ++q)
        emit4(outb, fl0 + 4 * q, make_float4(v[4*q], v[4*q+1], v[4*q+2], v[4*q+3]));
}

__device__ __forceinline__ void emit_row(float* __restrict__ outb, int fl0,
                                         float first, const float* __restrict__ cn) {
    emit4(outb, fl0, make_float4(first, cn[1], cn[2], cn[3]));
    #pragma unroll
    for (int q = 1; q < 8; ++q)
        emit4(outb, fl0 + 4 * q, make_float4(cn[4*q], cn[4*q+1], cn[4*q+2], cn[4*q+3]));
}

__device__ __forceinline__ void loadrow33(float* __restrict__ R,
                                          const float* __restrict__ base, int fb) {
    #pragma unroll
    for (int q = 0; q < 33; ++q)
        R[q] = base[(fb + q) * 12288];
}

// One thread per chain. Stride-32 recurrence on the 34-wide grid (faithful to ref),
// emitting the final cropped output directly.
__global__ __launch_bounds__(64) void scan_emit_k(const float* __restrict__ xt2,
                                                  float* __restrict__ out) {
    const int t  = blockIdx.x * 64 + threadIdx.x;   // chain = b*768 + c1
    const int b  = t / 768;
    const int c1 = t - b * 768;
    const float* base = xt2 + t;
    float* outb = out + (size_t)b * 786432;         // 3*512*512
    const int fl0 = c1 * 1156;

    float R0[33], R1[33], R2[33], pnv[32], cnv[32];
    loadrow33(R0, base, 0);
    loadrow33(R1, base, 32);
    loadrow33(R2, base, 64);
    emit32(outb, fl0, R0);                           // flats [0,32): originals

    // i = 1
    #pragma unroll
    for (int j = 1; j <= 31; ++j) {
        float L = (j >= 2) ? cnv[j - 1] : R1[0];
        float s = ((R0[j - 1] + R0[j]) + (R0[j + 1] + L))
                + ((R1[j + 1] + R2[j - 1]) + (R2[j] + R2[j + 1]));
        cnv[j] = s * 0.125f;
    }
    emit_row(outb, fl0 + 32, R1[0], cnv);

    for (int i = 2; i <= 30; ++i) {
        float prev0 = R1[0];
        #pragma unroll
        for (int q = 0; q < 33; ++q) R1[q] = R2[q];
        loadrow33(R2, base, (i + 1) * 32);
        #pragma unroll
        for (int j = 1; j <= 31; ++j) pnv[j] = cnv[j];
        #pragma unroll
        for (int j = 1; j <= 31; ++j) {
            float UL = (j >= 2)  ? pnv[j - 1] : prev0;
            float U  = pnv[j];
            float UR = (j <= 30) ? pnv[j + 1] : R1[0];
            float L  = (j >= 2)  ? cnv[j - 1] : R1[0];
            float s = ((UL + U) + (UR + L))
                    + ((R1[j + 1] + R2[j - 1]) + (R2[j] + R2[j + 1]));
            cnv[j] = s * 0.125f;
        }
        emit_row(outb, fl0 + i * 32, R1[0], cnv);
    }

    // flats [992,1024): originals, already in R2 (base 992)
    emit32(outb, fl0 + 992, R2);
    // flats [1024,1156): 132 originals, straight pass-through
    #pragma unroll
    for (int g = 0; g < 33; ++g) {
        int p0 = 1024 + g * 4;
        float4 o = make_float4(base[(p0 + 0) * 12288], base[(p0 + 1) * 12288],
                               base[(p0 + 2) * 12288], base[(p0 + 3) * 12288]);
        emit4(outb, fl0 + p0, o);
    }
}

extern "C" void kernel_launch(void* const* d_in, const int* in_sizes, int n_in,
                              void* d_out, int out_size, void* d_ws, size_t ws_size,
                              hipStream_t stream) {
    const float* x    = (const float*)d_in[0];
    const float* w    = (const float*)d_in[1];
    const float* bias = (const float*)d_in[2];
    float* out = (float*)d_out;
    float* xt2 = (float*)d_ws;   // 1156*12288 fp32 = 56.8 MB

    unsigned short* a_bf = (unsigned short*)d_out;          // 25.2 MB
    unsigned short* w_bf = a_bf + (size_t)16384 * 768;      // +1.18 MB

    convert_x_k<<<6144, 256, 0, stream>>>(x, a_bf);
    convert_w_k<<<288, 256, 0, stream>>>(w, w_bf);
    fill_borders2_k<<<6336, 256, 0, stream>>>(bias, xt2);
    conv_gemm_mfma_k<<<dim3(128, 6), 256, 0, stream>>>(a_bf, w_bf, bias, xt2);
    scan_emit_k<<<192, 64, 0, stream>>>(xt2, out);
}

// Round 4
// 94.352 us; speedup vs baseline: 1.3132x; 1.3132x over previous
//
#include <hip/hip_runtime.h>
#include <hip/hip_bf16.h>

// Pipeline (chain = b*768 + c1, 12288 chains; pos in [0,1156)):
//  d_ws  : xt [12288][1156] fp32 (per-chain rows) = 56.8 MB
//  d_out : scratch for bf16 A ([16384][768]) + bf16 W ([768][768]) during GEMM,
//          then fully overwritten with the final cropped output by scan_emit_k.
//  1) convert_x_k    : x fp32 -> A_bf16 [m=(b,ph,pw)][k=(c,py,px)]
//  2) convert_w_k    : w fp32 -> W_bf16
//  3) fill_borders_k : 132 border pos of each chain = bias[c1]
//  4) conv_gemm_mfma : 128x128 MFMA bf16 GEMM (+bias) -> xt interior
//  5) scan_emit_k    : wave-parallel recurrence (32 lanes per chain, Hillis-
//                      Steele scan for the left-neighbor term), fused crop emit.

typedef __attribute__((ext_vector_type(8))) short s8v;     // 8 bf16
typedef __attribute__((ext_vector_type(4))) float f4v;     // MFMA acc
typedef __attribute__((ext_vector_type(8))) unsigned short us8;

__device__ __forceinline__ unsigned short f2bf(float f) {
    __hip_bfloat16 h = __float2bfloat16(f);
    return *reinterpret_cast<unsigned short*>(&h);
}

__device__ __forceinline__ void gload_lds16(const void* g, void* l) {
    __builtin_amdgcn_global_load_lds(
        (const __attribute__((address_space(1))) unsigned int*)g,
        (__attribute__((address_space(3))) unsigned int*)l,
        16, 0, 0);
}

// x [16][3][512][512] f32 -> A_bf [16384][768] bf16
__global__ __launch_bounds__(256) void convert_x_k(const float* __restrict__ x,
                                                   unsigned short* __restrict__ a) {
    int g = blockIdx.x * 256 + threadIdx.x;
    int f = g << 3;
    int wc = f & 511;
    int h  = (f >> 9) & 511;
    int cb = f >> 18;
    int c  = cb % 3, b = cb / 3;
    const float4 v0 = *(const float4*)(x + f);
    const float4 v1 = *(const float4*)(x + f + 4);
    int m = (b << 10) + ((h >> 4) << 5) + (wc >> 4);
    int k = (c << 8) + ((h & 15) << 4) + (wc & 15);
    us8 o;
    o[0] = f2bf(v0.x); o[1] = f2bf(v0.y); o[2] = f2bf(v0.z); o[3] = f2bf(v0.w);
    o[4] = f2bf(v1.x); o[5] = f2bf(v1.y); o[6] = f2bf(v1.z); o[7] = f2bf(v1.w);
    *(us8*)(a + (size_t)m * 768 + k) = o;
}

__global__ __launch_bounds__(256) void convert_w_k(const float* __restrict__ w,
                                                   unsigned short* __restrict__ o) {
    int g = blockIdx.x * 256 + threadIdx.x;
    int f = g << 3;
    const float4 v0 = *(const float4*)(w + f);
    const float4 v1 = *(const float4*)(w + f + 4);
    us8 u;
    u[0] = f2bf(v0.x); u[1] = f2bf(v0.y); u[2] = f2bf(v0.z); u[3] = f2bf(v0.w);
    u[4] = f2bf(v1.x); u[5] = f2bf(v1.y); u[6] = f2bf(v1.z); u[7] = f2bf(v1.w);
    *(us8*)(o + f) = u;
}

__global__ __launch_bounds__(256) void fill_borders_k(const float* __restrict__ bias,
                                                      float* __restrict__ xt) {
    int tid = blockIdx.x * 256 + threadIdx.x;      // 132 * 12288 exactly
    int e  = tid % 132;
    int r  = tid / 132;
    int c1 = r % 768;
    int pos;
    if (e < 34)       pos = e;                      // h1 == 0
    else if (e < 68)  pos = 1122 + (e - 34);        // h1 == 33
    else if (e < 100) pos = (e - 67) * 34;          // w1 == 0, h1 = 1..32
    else              pos = (e - 99) * 34 + 33;     // w1 == 33, h1 = 1..32
    xt[(size_t)r * 1156 + pos] = bias[c1];
}

// C[m][n] = sum_k A[m][k] * W[n][k]; 128x128 tile, BK=32, 4 waves
__global__ __launch_bounds__(256) void conv_gemm_mfma_k(const unsigned short* __restrict__ A,
                                                        const unsigned short* __restrict__ W,
                                                        const float* __restrict__ bias,
                                                        float* __restrict__ xt) {
    __shared__ __align__(16) unsigned short As[128 * 32];
    __shared__ __align__(16) unsigned short Bs[128 * 32];
    const int tid  = threadIdx.x;
    const int lane = tid & 63, wv = tid >> 6;
    const int wr = wv >> 1, wc = wv & 1;
    const int m0 = blockIdx.x << 7, n0 = blockIdx.y << 7;

    f4v acc[4][4] = {};

    const unsigned short* gA = A + (size_t)(m0 + (wv << 5) + (lane >> 2)) * 768 + ((lane & 3) << 3);
    const unsigned short* gB = W + (size_t)(n0 + (wv << 5) + (lane >> 2)) * 768 + ((lane & 3) << 3);
    unsigned short* lA = As + (wv << 10);
    unsigned short* lB = Bs + (wv << 10);

    for (int k0 = 0; k0 < 768; k0 += 32) {
        gload_lds16(gA + k0,            lA);
        gload_lds16(gA + k0 + 16 * 768, lA + 512);
        gload_lds16(gB + k0,            lB);
        gload_lds16(gB + k0 + 16 * 768, lB + 512);
        __syncthreads();
        s8v a[4], b[4];
        #pragma unroll
        for (int mi = 0; mi < 4; ++mi)
            a[mi] = *(const s8v*)(As + (((wr << 6) + (mi << 4) + (lane & 15)) << 5) + ((lane >> 4) << 3));
        #pragma unroll
        for (int ni = 0; ni < 4; ++ni)
            b[ni] = *(const s8v*)(Bs + (((wc << 6) + (ni << 4) + (lane & 15)) << 5) + ((lane >> 4) << 3));
        #pragma unroll
        for (int mi = 0; mi < 4; ++mi)
            #pragma unroll
            for (int ni = 0; ni < 4; ++ni)
                acc[mi][ni] = __builtin_amdgcn_mfma_f32_16x16x32_bf16(a[mi], b[ni], acc[mi][ni], 0, 0, 0);
        __syncthreads();
    }

    #pragma unroll
    for (int ni = 0; ni < 4; ++ni) {
        int n = n0 + (wc << 6) + (ni << 4) + (lane & 15);
        float bv = bias[n];
        #pragma unroll
        for (int mi = 0; mi < 4; ++mi) {
            #pragma unroll
            for (int r = 0; r < 4; ++r) {
                int m  = m0 + (wr << 6) + (mi << 4) + ((lane >> 4) << 2) + r;
                int bb = m >> 10, ph = (m >> 5) & 31, pw = m & 31;
                int pos = (ph + 1) * 34 + (pw + 1);
                xt[(size_t)(bb * 768 + n) * 1156 + pos] = acc[mi][ni][r] + bv;
            }
        }
    }
}

// Wave-parallel scan + fused crop: one 32-lane group per chain.
// Flat recurrence grid is 32-wide: flat = i*32 + j; updated set i=1..30, j=1..31.
// new[i][j] = (pn[j-1]+pn[j]+pn[j+1] + new[i][j-1] + orig[i*32+j+1]
//              + orig[(i+1)*32+j-1] + orig[(i+1)*32+j] + orig[(i+1)*32+j+1]) / 8
// The new[i][j-1] term is solved by a 5-step Hillis-Steele linear-recurrence
// scan with exact power-of-two multipliers 8^-s.
__global__ __launch_bounds__(256) void scan_emit_k(const float* __restrict__ xt,
                                                   float* __restrict__ out) {
    const int grp = (blockIdx.x * 256 + threadIdx.x) >> 5;   // chain
    const int j   = threadIdx.x & 31;
    const int b   = grp / 768;
    const int c1  = grp - b * 768;
    const float* base = xt + (size_t)grp * 1156;
    float* outb = out + (size_t)b * 786432;                  // 3*512*512
    const int fl0 = c1 * 1156;

    auto emit = [&](int fl, float v) {
        unsigned int c   = (fl >= 591872) ? 2u : (fl >= 295936 ? 1u : 0u);
        unsigned int rem = (unsigned int)fl - c * 295936u;
        unsigned int y   = rem / 544u;
        unsigned int xx  = rem - y * 544u;
        if (y >= 16u && y < 528u && xx >= 16u && xx < 528u)
            outb[(size_t)c * 262144 + (y - 16) * 512 + (xx - 16)] = v;
    };

    float r0 = base[j];            // row 0 originals
    float co = base[32 + j];       // row 1 originals (current)
    float no = base[64 + j];       // row 2 originals (next)
    emit(fl0 + j, r0);
    float pn = r0;                 // "previous new" row; row 0 stays original
    float po_head = __shfl(r0, 0, 32);   // orig[(i-1)*32]

    for (int i = 1; i <= 30; ++i) {
        float co_head = __shfl(co, 0, 32);          // orig[i*32]
        float no_head = __shfl(no, 0, 32);          // orig[(i+1)*32]
        float n2_head = base[(i + 2) * 32];         // orig[(i+2)*32] (uniform)
        float UL = __shfl_up(pn, 1, 32);   if (j == 1)  UL = po_head;
        float U  = pn;
        float UR = __shfl_down(pn, 1, 32); if (j == 31) UR = co_head;
        float Rr = __shfl_down(co, 1, 32); if (j == 31) Rr = no_head;
        float D1 = __shfl_up(no, 1, 32);   // j=1 -> lane0's no = orig[(i+1)*32]
        float D2 = no;
        float D3 = __shfl_down(no, 1, 32); if (j == 31) D3 = n2_head;
        float bv = (((UL + U) + (UR + Rr)) + ((D1 + D2) + D3)) * 0.125f;
        if (j == 1) bv += co_head * 0.125f;         // left neighbor of j=1 is orig
        // x[j] = bv[j] + (1/8) x[j-1], lanes 1..31
        float t;
        t = __shfl_up(bv, 1, 32);  bv += (j > 1)  ? 0.125f * t : 0.f;
        t = __shfl_up(bv, 2, 32);  bv += (j > 2)  ? 0.015625f * t : 0.f;
        t = __shfl_up(bv, 4, 32);  bv += (j > 4)  ? 2.44140625e-4f * t : 0.f;
        t = __shfl_up(bv, 8, 32);  bv += (j > 8)  ? 5.9604644775390625e-8f * t : 0.f;
        t = __shfl_up(bv, 16, 32); bv += (j > 16) ? 3.552713678800501e-15f * t : 0.f;
        emit(fl0 + i * 32 + j, (j == 0) ? co : bv);
        pn = bv;
        po_head = co_head;
        co = no;
        no = base[(i + 2) * 32 + j];               // row i+2 (i=30 -> row 32, OK)
    }
    // After loop: co = row 31 (flats 992..1023), no = row 32 (1024..1055) — originals.
    emit(fl0 + 992 + j, co);
    emit(fl0 + 1024 + j, no);
    emit(fl0 + 1056 + j, base[1056 + j]);
    emit(fl0 + 1088 + j, base[1088 + j]);
    emit(fl0 + 1120 + j, base[1120 + j]);
    if (j < 4) emit(fl0 + 1152 + j, base[1152 + j]);
}

extern "C" void kernel_launch(void* const* d_in, const int* in_sizes, int n_in,
                              void* d_out, int out_size, void* d_ws, size_t ws_size,
                              hipStream_t stream) {
    const float* x    = (const float*)d_in[0];
    const float* w    = (const float*)d_in[1];
    const float* bias = (const float*)d_in[2];
    float* out = (float*)d_out;
    float* xt  = (float*)d_ws;   // 12288*1156 fp32 = 56.8 MB

    unsigned short* a_bf = (unsigned short*)d_out;          // 25.2 MB
    unsigned short* w_bf = a_bf + (size_t)16384 * 768;      // +1.18 MB

    convert_x_k<<<6144, 256, 0, stream>>>(x, a_bf);
    convert_w_k<<<288, 256, 0, stream>>>(w, w_bf);
    fill_borders_k<<<6336, 256, 0, stream>>>(bias, xt);
    conv_gemm_mfma_k<<<dim3(128, 6), 256, 0, stream>>>(a_bf, w_bf, bias, xt);
    scan_emit_k<<<1536, 256, 0, stream>>>(xt, out);
}

// Round 5
// 90.744 us; speedup vs baseline: 1.3654x; 1.0398x over previous
//
#include <hip/hip_runtime.h>
#include <hip/hip_bf16.h>

// Pipeline (chain = b*768 + c1, 12288 chains; pos in [0,1156)):
//  d_ws  : xt [12288][1156] fp32 (per-chain rows) = 56.8 MB
//  d_out : scratch for bf16 A ([16384][768]) + bf16 W ([768][768]) during GEMM,
//          then fully overwritten with the final cropped output by scan_emit_k.
//  1) prep_k         : convert_x + convert_w + fill_borders in one launch
//  2) conv_gemm_mfma : 128x128 MFMA bf16 GEMM (+bias), 2-phase LDS double-buffer
//  3) scan_emit_k    : wave-parallel recurrence (32 lanes per chain, 3-step
//                      Hillis-Steele for left-neighbor term, 4-row register
//                      prefetch pipeline), fused crop emit.

typedef __attribute__((ext_vector_type(8))) short s8v;     // 8 bf16
typedef __attribute__((ext_vector_type(4))) float f4v;     // MFMA acc
typedef __attribute__((ext_vector_type(8))) unsigned short us8;

__device__ __forceinline__ unsigned short f2bf(float f) {
    __hip_bfloat16 h = __float2bfloat16(f);
    return *reinterpret_cast<unsigned short*>(&h);
}

__device__ __forceinline__ void gload_lds16(const void* g, void* l) {
    __builtin_amdgcn_global_load_lds(
        (const __attribute__((address_space(1))) unsigned int*)g,
        (__attribute__((address_space(3))) unsigned int*)l,
        16, 0, 0);
}

// block ranges: [0,6144) convert_x, [6144,6432) convert_w, [6432,12768) borders
__global__ __launch_bounds__(256) void prep_k(const float* __restrict__ x,
                                              const float* __restrict__ w,
                                              const float* __restrict__ bias,
                                              unsigned short* __restrict__ a_bf,
                                              unsigned short* __restrict__ w_bf,
                                              float* __restrict__ xt) {
    const int bid = blockIdx.x;
    if (bid < 6144) {
        // x [16][3][512][512] f32 -> A_bf [16384][768] bf16, m=(b,ph,pw), k=(c,py,px)
        int g = bid * 256 + threadIdx.x;
        int f = g << 3;
        int wc = f & 511;
        int h  = (f >> 9) & 511;
        int cb = f >> 18;
        int c  = cb % 3, b = cb / 3;
        const float4 v0 = *(const float4*)(x + f);
        const float4 v1 = *(const float4*)(x + f + 4);
        int m = (b << 10) + ((h >> 4) << 5) + (wc >> 4);
        int k = (c << 8) + ((h & 15) << 4) + (wc & 15);
        us8 o;
        o[0] = f2bf(v0.x); o[1] = f2bf(v0.y); o[2] = f2bf(v0.z); o[3] = f2bf(v0.w);
        o[4] = f2bf(v1.x); o[5] = f2bf(v1.y); o[6] = f2bf(v1.z); o[7] = f2bf(v1.w);
        *(us8*)(a_bf + (size_t)m * 768 + k) = o;
    } else if (bid < 6432) {
        int g = (bid - 6144) * 256 + threadIdx.x;
        int f = g << 3;
        const float4 v0 = *(const float4*)(w + f);
        const float4 v1 = *(const float4*)(w + f + 4);
        us8 u;
        u[0] = f2bf(v0.x); u[1] = f2bf(v0.y); u[2] = f2bf(v0.z); u[3] = f2bf(v0.w);
        u[4] = f2bf(v1.x); u[5] = f2bf(v1.y); u[6] = f2bf(v1.z); u[7] = f2bf(v1.w);
        *(us8*)(w_bf + f) = u;
    } else {
        int tid = (bid - 6432) * 256 + threadIdx.x;   // 132 * 12288 exactly
        int e  = tid % 132;
        int r  = tid / 132;
        int c1 = r % 768;
        int pos;
        if (e < 34)       pos = e;                      // h1 == 0
        else if (e < 68)  pos = 1122 + (e - 34);        // h1 == 33
        else if (e < 100) pos = (e - 67) * 34;          // w1 == 0, h1 = 1..32
        else              pos = (e - 99) * 34 + 33;     // w1 == 33, h1 = 1..32
        xt[(size_t)r * 1156 + pos] = bias[c1];
    }
}

// C[m][n] = sum_k A[m][k] * W[n][k]; 128x128 tile, BK=32, 4 waves,
// 2-phase LDS double buffer (issue next stage before current compute).
__global__ __launch_bounds__(256) void conv_gemm_mfma_k(const unsigned short* __restrict__ A,
                                                        const unsigned short* __restrict__ W,
                                                        const float* __restrict__ bias,
                                                        float* __restrict__ xt) {
    __shared__ __align__(16) unsigned short As[2][128 * 32];
    __shared__ __align__(16) unsigned short Bs[2][128 * 32];
    const int tid  = threadIdx.x;
    const int lane = tid & 63, wv = tid >> 6;
    const int wr = wv >> 1, wc = wv & 1;
    const int m0 = blockIdx.x << 7, n0 = blockIdx.y << 7;

    f4v acc[4][4] = {};

    const unsigned short* gA = A + (size_t)(m0 + (wv << 5) + (lane >> 2)) * 768 + ((lane & 3) << 3);
    const unsigned short* gB = W + (size_t)(n0 + (wv << 5) + (lane >> 2)) * 768 + ((lane & 3) << 3);

    auto stage = [&](int buf, int k0) {
        gload_lds16(gA + k0,            As[buf] + (wv << 10));
        gload_lds16(gA + k0 + 16 * 768, As[buf] + (wv << 10) + 512);
        gload_lds16(gB + k0,            Bs[buf] + (wv << 10));
        gload_lds16(gB + k0 + 16 * 768, Bs[buf] + (wv << 10) + 512);
    };

    stage(0, 0);
    asm volatile("s_waitcnt vmcnt(0)" ::: "memory");
    __syncthreads();

    int cur = 0;
    for (int t = 0; t < 24; ++t) {
        if (t < 23) stage(cur ^ 1, (t + 1) << 5);      // prefetch next K-tile
        s8v a[4], b[4];
        #pragma unroll
        for (int mi = 0; mi < 4; ++mi)
            a[mi] = *(const s8v*)(As[cur] + (((wr << 6) + (mi << 4) + (lane & 15)) << 5) + ((lane >> 4) << 3));
        #pragma unroll
        for (int ni = 0; ni < 4; ++ni)
            b[ni] = *(const s8v*)(Bs[cur] + (((wc << 6) + (ni << 4) + (lane & 15)) << 5) + ((lane >> 4) << 3));
        #pragma unroll
        for (int mi = 0; mi < 4; ++mi)
            #pragma unroll
            for (int ni = 0; ni < 4; ++ni)
                acc[mi][ni] = __builtin_amdgcn_mfma_f32_16x16x32_bf16(a[mi], b[ni], acc[mi][ni], 0, 0, 0);
        asm volatile("s_waitcnt vmcnt(0)" ::: "memory");
        __syncthreads();
        cur ^= 1;
    }

    #pragma unroll
    for (int ni = 0; ni < 4; ++ni) {
        int n = n0 + (wc << 6) + (ni << 4) + (lane & 15);
        float bv = bias[n];
        #pragma unroll
        for (int mi = 0; mi < 4; ++mi) {
            #pragma unroll
            for (int r = 0; r < 4; ++r) {
                int m  = m0 + (wr << 6) + (mi << 4) + ((lane >> 4) << 2) + r;
                int bb = m >> 10, ph = (m >> 5) & 31, pw = m & 31;
                int pos = (ph + 1) * 34 + (pw + 1);
                xt[(size_t)(bb * 768 + n) * 1156 + pos] = acc[mi][ni][r] + bv;
            }
        }
    }
}

// Wave-parallel scan + fused crop: one 32-lane group per chain.
// new[i][j] = (pn[j-1]+pn[j]+pn[j+1] + new[i][j-1] + orig[i*32+j+1]
//              + orig[(i+1)*32+j-1..j+1]) / 8,  i=1..30, j=1..31.
// Left-neighbor term solved by 3-step Hillis-Steele (8^-s multipliers; dropped
// steps 8/16 carry coeff <= 8^-8 ~ 6e-8 -> negligible). 4-row register
// prefetch pipeline hides HBM latency.
__global__ __launch_bounds__(256) void scan_emit_k(const float* __restrict__ xt,
                                                   float* __restrict__ out) {
    const int grp = (blockIdx.x * 256 + threadIdx.x) >> 5;   // chain
    const int j   = threadIdx.x & 31;
    const int b   = grp / 768;
    const int c1  = grp - b * 768;
    const float* base = xt + (size_t)grp * 1156;
    float* outb = out + (size_t)b * 786432;                  // 3*512*512
    const int fl0 = c1 * 1156;

    auto emit = [&](int fl, float v) {
        unsigned int c   = (fl >= 591872) ? 2u : (fl >= 295936 ? 1u : 0u);
        unsigned int rem = (unsigned int)fl - c * 295936u;
        unsigned int y   = rem / 544u;
        unsigned int xx  = rem - y * 544u;
        if (y >= 16u && y < 528u && xx >= 16u && xx < 528u)
            outb[(size_t)c * 262144 + (y - 16) * 512 + (xx - 16)] = v;
    };

    // prefetch pipeline: rows i, i+1, i+2, i+3 live; load row i+4 each iter
    float r0 = base[j];            // row 0
    float co = base[32 + j];       // row 1
    float no = base[64 + j];       // row 2
    float o2 = base[96 + j];       // row 3
    float o3 = base[128 + j];      // row 4
    emit(fl0 + j, r0);
    float pn = r0;                 // row 0 stays original
    float po_head = __shfl(r0, 0, 32);

    for (int i = 1; i <= 30; ++i) {
        float ld = base[(i + 4) * 32 + j];          // row i+4 (max row 34 < 36)
        float co_head = __shfl(co, 0, 32);          // orig[i*32]
        float no_head = __shfl(no, 0, 32);          // orig[(i+1)*32]
        float n2_head = __shfl(o2, 0, 32);          // orig[(i+2)*32]
        float UL = __shfl_up(pn, 1, 32);   if (j == 1)  UL = po_head;
        float U  = pn;
        float UR = __shfl_down(pn, 1, 32); if (j == 31) UR = co_head;
        float Rr = __shfl_down(co, 1, 32); if (j == 31) Rr = no_head;
        float D1 = __shfl_up(no, 1, 32);   // j=1 -> lane0's no = orig[(i+1)*32]
        float D2 = no;
        float D3 = __shfl_down(no, 1, 32); if (j == 31) D3 = n2_head;
        float bv = (((UL + U) + (UR + Rr)) + ((D1 + D2) + D3)) * 0.125f;
        if (j == 1) bv += co_head * 0.125f;         // left neighbor of j=1 is orig
        float t;
        t = __shfl_up(bv, 1, 32);  bv += (j > 1) ? 0.125f * t : 0.f;
        t = __shfl_up(bv, 2, 32);  bv += (j > 2) ? 0.015625f * t : 0.f;
        t = __shfl_up(bv, 4, 32);  bv += (j > 4) ? 2.44140625e-4f * t : 0.f;
        emit(fl0 + i * 32 + j, (j == 0) ? co : bv);
        pn = bv;
        po_head = co_head;
        co = no; no = o2; o2 = o3; o3 = ld;
    }
    // regs now: co=row31, no=row32, o2=row33, o3=row34 — all originals
    emit(fl0 +  992 + j, co);
    emit(fl0 + 1024 + j, no);
    emit(fl0 + 1056 + j, o2);
    emit(fl0 + 1088 + j, o3);
    emit(fl0 + 1120 + j, base[1120 + j]);
    if (j < 4) emit(fl0 + 1152 + j, base[1152 + j]);
}

extern "C" void kernel_launch(void* const* d_in, const int* in_sizes, int n_in,
                              void* d_out, int out_size, void* d_ws, size_t ws_size,
                              hipStream_t stream) {
    const float* x    = (const float*)d_in[0];
    const float* w    = (const float*)d_in[1];
    const float* bias = (const float*)d_in[2];
    float* out = (float*)d_out;
    float* xt  = (float*)d_ws;   // 12288*1156 fp32 = 56.8 MB

    unsigned short* a_bf = (unsigned short*)d_out;          // 25.2 MB
    unsigned short* w_bf = a_bf + (size_t)16384 * 768;      // +1.18 MB

    prep_k<<<12768, 256, 0, stream>>>(x, w, bias, a_bf, w_bf, xt);
    conv_gemm_mfma_k<<<dim3(128, 6), 256, 0, stream>>>(a_bf, w_bf, bias, xt);
    scan_emit_k<<<1536, 256, 0, stream>>>(xt, out);
}